// Round 3
// baseline (2776.168 us; speedup 1.0000x reference)
//
#include <hip/hip_runtime.h>
#include <stdint.h>

#define B_ 4
#define S_ 1024
#define D_ 1024
#define H_ 16
#define DK_ 64

// ---------------------------------------------------------------------------
// C = A @ W^T + bias. A: [M,K] f32 row-major. W: [N,K] f32 row-major.
// OMODE 0: C[m*N+n] f32. OMODE 1: scatter to [b][h][s][d] (m=b*S+s, n=h*64+d).
// Block: 256 threads -> 64x64 tile, thread computes 4x4. K-chunk = 16.
// ---------------------------------------------------------------------------
template <int OMODE>
__global__ __launch_bounds__(256) void gemm_bias(const float* __restrict__ A,
                                                 const float* __restrict__ W,
                                                 const float* __restrict__ bias,
                                                 float* __restrict__ Cout,
                                                 int M, int N, int K) {
    __shared__ float As[16][68];   // [k][m]
    __shared__ float Bs[16][68];   // [k][n]
    const int t  = threadIdx.x;
    const int m0 = blockIdx.y * 64;
    const int n0 = blockIdx.x * 64;
    const int tn = t & 15, tm = t >> 4;
    const int lr  = t >> 2;          // 0..63 load row
    const int lc  = (t & 3) * 4;     // 0,4,8,12 load col group
    float acc[4][4] = {};

    for (int kc = 0; kc < K; kc += 16) {
        {
            float4 u = *(const float4*)(A + (size_t)(m0 + lr) * K + kc + lc);
            As[lc + 0][lr] = u.x;
            As[lc + 1][lr] = u.y;
            As[lc + 2][lr] = u.z;
            As[lc + 3][lr] = u.w;
        }
        {
            float4 u = *(const float4*)(W + (size_t)(n0 + lr) * K + kc + lc);
            Bs[lc + 0][lr] = u.x;
            Bs[lc + 1][lr] = u.y;
            Bs[lc + 2][lr] = u.z;
            Bs[lc + 3][lr] = u.w;
        }
        __syncthreads();
#pragma unroll
        for (int kk = 0; kk < 16; ++kk) {
            float4 a = *(const float4*)&As[kk][tm * 4];
            float4 b = *(const float4*)&Bs[kk][tn * 4];
            float av[4] = {a.x, a.y, a.z, a.w};
            float bv[4] = {b.x, b.y, b.z, b.w};
#pragma unroll
            for (int i = 0; i < 4; ++i)
#pragma unroll
                for (int j = 0; j < 4; ++j) acc[i][j] += av[i] * bv[j];
        }
        __syncthreads();
    }

#pragma unroll
    for (int i = 0; i < 4; ++i) {
        const int m = m0 + tm * 4 + i;
#pragma unroll
        for (int j = 0; j < 4; ++j) {
            const int n   = n0 + tn * 4 + j;
            const float v = acc[i][j] + bias[n];
            if (OMODE == 0) {
                Cout[(size_t)m * N + n] = v;
            } else {
                const int b = m >> 10, s = m & (S_ - 1);
                const int h = n >> 6, d = n & 63;
                Cout[(((size_t)b * H_ + h) * S_ + s) * DK_ + d] = v;
            }
        }
    }
}

// ---------------------------------------------------------------------------
// scores + softmax. Block: 256 thr = 8 rows x 32 j-lanes. Softmax in fp32,
// fp32 attn written straight to output region in [h*B+b][i][j] layout.
// ---------------------------------------------------------------------------
__global__ __launch_bounds__(256) void attn_softmax(const float* __restrict__ Qh,
                                                    const float* __restrict__ Kh,
                                                    float* __restrict__ attn) {
    const int bh = blockIdx.y;           // b*H + h
    const int b = bh >> 4, h = bh & 15;
    const int i0 = blockIdx.x * 8;
    const int t  = threadIdx.x;
    const int ti = t >> 5;               // 0..7 row
    const int tj = t & 31;               // 0..31 j lane

    __shared__ float Qs[8 * DK_];        // 2 KB
    __shared__ float Ss[8 * S_];         // 32 KB

    if (t < 128)
        ((float4*)Qs)[t] = ((const float4*)(Qh + ((size_t)bh * S_ + i0) * DK_))[t];
    __syncthreads();

    const float* Kbase = Kh + (size_t)bh * S_ * DK_;
    const float* qrow  = Qs + ti * DK_;

    float mx = -1e30f;
    for (int m = 0; m < 32; ++m) {
        const int j = tj + (m << 5);
        const float* krow = Kbase + (size_t)j * DK_;
        float acc = 0.f;
#pragma unroll
        for (int kk = 0; kk < DK_; kk += 4) {
            float4 kv = *(const float4*)(krow + kk);
            float4 qv = *(const float4*)(qrow + kk);
            acc += qv.x * kv.x + qv.y * kv.y + qv.z * kv.z + qv.w * kv.w;
        }
        Ss[ti * S_ + j] = acc;
        mx = fmaxf(mx, acc);
    }
#pragma unroll
    for (int o = 1; o < 32; o <<= 1) mx = fmaxf(mx, __shfl_xor(mx, o, 64));

    float sum = 0.f;
    for (int m = 0; m < 32; ++m) {
        const int j = tj + (m << 5);
        const float e = __expf(Ss[ti * S_ + j] - mx);
        Ss[ti * S_ + j] = e;
        sum += e;
    }
#pragma unroll
    for (int o = 1; o < 32; o <<= 1) sum += __shfl_xor(sum, o, 64);
    const float inv = 1.0f / sum;

    float* dst = attn + ((size_t)(h * B_ + b) * S_ + i0 + ti) * S_;
    for (int m = 0; m < 32; ++m) {
        const int j = tj + (m << 5);
        dst[j] = Ss[ti * S_ + j] * inv;
    }
}

// ---------------------------------------------------------------------------
// ctx = attn @ V per (b,h). attn read back fp32 from the output region.
// Block: 256 thr computes 32 rows x 64 d tile. Output -> ctx[b][s][h*64+d].
// ---------------------------------------------------------------------------
__global__ __launch_bounds__(256) void attn_pv(const float* __restrict__ attn,
                                               const float* __restrict__ Vh,
                                               float* __restrict__ ctx) {
    const int bh = blockIdx.y;
    const int b = bh >> 4, h = bh & 15;
    const int i0 = blockIdx.x * 32;
    const int t  = threadIdx.x;
    const int i  = t & 31;
    const int d0 = (t >> 5) * 8;

    __shared__ float As[32][33];
    __shared__ float Vs[32][64];

    float acc[8] = {};
    const float* abase = attn + ((size_t)(h * B_ + b) * S_ + i0) * S_;
    const float* vbase = Vh + (size_t)bh * S_ * DK_;
    const int lr  = t >> 3;          // 0..31
    const int lc4 = (t & 7) * 4;
    const int lc8 = (t & 7) * 8;

    for (int jc = 0; jc < 32; ++jc) {
        const int j0 = jc * 32;
        {
            float4 u = *(const float4*)(abase + (size_t)lr * S_ + j0 + lc4);
            As[lr][lc4 + 0] = u.x;
            As[lr][lc4 + 1] = u.y;
            As[lr][lc4 + 2] = u.z;
            As[lr][lc4 + 3] = u.w;
        }
        {
            const float4* vp = (const float4*)(vbase + (size_t)(j0 + lr) * DK_ + lc8);
            float4 v0 = vp[0], v1 = vp[1];
            *(float4*)&Vs[lr][lc8]     = v0;
            *(float4*)&Vs[lr][lc8 + 4] = v1;
        }
        __syncthreads();
#pragma unroll
        for (int jj = 0; jj < 32; ++jj) {
            const float a = As[i][jj];
            float4 v0 = *(const float4*)&Vs[jj][d0];
            float4 v1 = *(const float4*)&Vs[jj][d0 + 4];
            acc[0] += a * v0.x; acc[1] += a * v0.y; acc[2] += a * v0.z; acc[3] += a * v0.w;
            acc[4] += a * v1.x; acc[5] += a * v1.y; acc[6] += a * v1.z; acc[7] += a * v1.w;
        }
        __syncthreads();
    }
    float* crow = ctx + ((size_t)b * S_ + i0 + i) * D_ + h * DK_ + d0;
    *(float4*)crow       = make_float4(acc[0], acc[1], acc[2], acc[3]);
    *(float4*)(crow + 4) = make_float4(acc[4], acc[5], acc[6], acc[7]);
}

// ---------------------------------------------------------------------------
// y = LayerNorm(x + residual_q) * gamma + beta  (one block per row of 1024)
// ---------------------------------------------------------------------------
__global__ __launch_bounds__(256) void ln_kernel(const float* __restrict__ X,
                                                 const float* __restrict__ q,
                                                 const float* __restrict__ gamma,
                                                 const float* __restrict__ beta,
                                                 float* __restrict__ y) {
    const int row = blockIdx.x;
    const int t   = threadIdx.x;
    const size_t base = (size_t)row * D_;

    float4 xv = *(const float4*)(X + base + t * 4);
    float4 qv = *(const float4*)(q + base + t * 4);
    const float x0 = xv.x + qv.x, x1 = xv.y + qv.y;
    const float x2 = xv.z + qv.z, x3 = xv.w + qv.w;

    float sum = x0 + x1 + x2 + x3;
    float sq  = x0 * x0 + x1 * x1 + x2 * x2 + x3 * x3;
#pragma unroll
    for (int o = 32; o > 0; o >>= 1) {
        sum += __shfl_xor(sum, o, 64);
        sq  += __shfl_xor(sq, o, 64);
    }
    __shared__ float red[8];
    const int wv = t >> 6;
    if ((t & 63) == 0) { red[wv] = sum; red[4 + wv] = sq; }
    __syncthreads();
    sum = red[0] + red[1] + red[2] + red[3];
    sq  = red[4] + red[5] + red[6] + red[7];

    const float mu  = sum * (1.0f / 1024.0f);
    const float var = sq * (1.0f / 1024.0f) - mu * mu;
    const float rs  = rsqrtf(var + 1e-5f);

    float4 gv = *(const float4*)(gamma + t * 4);
    float4 bv = *(const float4*)(beta + t * 4);
    float4 o;
    o.x = (x0 - mu) * rs * gv.x + bv.x;
    o.y = (x1 - mu) * rs * gv.y + bv.y;
    o.z = (x2 - mu) * rs * gv.z + bv.z;
    o.w = (x3 - mu) * rs * gv.w + bv.w;
    *(float4*)(y + base + t * 4) = o;
}

extern "C" void kernel_launch(void* const* d_in, const int* in_sizes, int n_in,
                              void* d_out, int out_size, void* d_ws, size_t ws_size,
                              hipStream_t stream) {
    const float* q    = (const float*)d_in[0];
    const float* k    = (const float*)d_in[1];
    const float* v    = (const float*)d_in[2];
    const float* Wq   = (const float*)d_in[3];
    const float* bq   = (const float*)d_in[4];
    const float* Wk   = (const float*)d_in[5];
    const float* bk   = (const float*)d_in[6];
    const float* Wv   = (const float*)d_in[7];
    const float* bv   = (const float*)d_in[8];
    const float* Wfc  = (const float*)d_in[9];
    const float* bfc  = (const float*)d_in[10];
    const float* gamma= (const float*)d_in[11];
    const float* beta = (const float*)d_in[12];

    float* y_out    = (float*)d_out;
    float* attn_out = (float*)d_out + (size_t)B_ * S_ * D_;   // fp32 outputs

    // Workspace (48 MB): Qh/Kh/Vh, then reuse Kh->ctx, Qh->xbuf.
    float* ws   = (float*)d_ws;
    float* Qh   = ws;                 // 16 MB  [b][h][s][64]
    float* Kh   = ws + 4194304;       // 16 MB  [b][h][s][64]
    float* Vh   = ws + 8388608;       // 16 MB  [b][h][s][64]
    float* ctx  = Kh;                 // reuse (Kh dead after attn_softmax)
    float* xbuf = Qh;                 // reuse (Qh dead after attn_softmax)

    const dim3 gg(16, 64), bb(256);
    gemm_bias<1><<<gg, bb, 0, stream>>>(q, Wq, bq, Qh, 4096, 1024, 1024);
    gemm_bias<1><<<gg, bb, 0, stream>>>(k, Wk, bk, Kh, 4096, 1024, 1024);
    gemm_bias<1><<<gg, bb, 0, stream>>>(v, Wv, bv, Vh, 4096, 1024, 1024);

    attn_softmax<<<dim3(128, 64), 256, 0, stream>>>(Qh, Kh, attn_out);
    attn_pv<<<dim3(32, 64), 256, 0, stream>>>(attn_out, Vh, ctx);

    gemm_bias<0><<<gg, bb, 0, stream>>>(ctx, Wfc, bfc, xbuf, 4096, 1024, 1024);
    ln_kernel<<<4096, 256, 0, stream>>>(xbuf, q, gamma, beta, y_out);
}